// Round 13
// baseline (5277.760 us; speedup 1.0000x reference)
//
#include <hip/hip_runtime.h>
#include <cstddef>

#define HID   512
#define G4    2048   // 4*HID
#define NB    32     // batch
#define SEQL  1024
#define INPD  512
#define NBLK  128    // persistent blocks: block j owns hidden units [4j, 4j+4)
#define TPB   512

typedef _Float16 half8 __attribute__((ext_vector_type(8)));
typedef float    f32x4 __attribute__((ext_vector_type(4)));

__device__ __forceinline__ float sigm(float x) {
    return 1.0f / (1.0f + __expf(-x));
}
__device__ __forceinline__ float tanh_fast(float x) {
    float e = __expf(-2.0f * fabsf(x));
    float t = (1.0f - e) / (1.0f + e);
    return copysignf(t, x);
}

// Permuted gate index: g' = j*16 + type*4 + uu  (block j's 16 gates contiguous)
__device__ __forceinline__ int orig_gate(int gp) {
    int r = gp & 15;
    return (r >> 2) * HID + (gp >> 4) * 4 + (r & 3);
}

// ---- one-time: W_hh fp32 [2048][512] -> fp16, per-block unit-major layout:
//      wh[j][p][k], p = uu*4 + type   (uu = unit-within-block, type = gate)
__global__ __launch_bounds__(256) void conv_whh(const float* __restrict__ whh,
                                                _Float16* __restrict__ wh) {
    int e = blockIdx.x * 256 + threadIdx.x;   // e < 2048*512
    int R = e >> 9, k = e & 511;
    int type = R >> 9, rem = R & 511;
    int j = rem >> 2, uu = rem & 3;
    int p = uu * 4 + type;
    wh[((size_t)j * 16 + p) * 512 + k] = (_Float16)whh[e];
}

// ---- one-time: h0 fp32 -> fp16 into hbuf buffer 0
__global__ __launch_bounds__(256) void conv_h0(const float* __restrict__ h0,
                                               _Float16* __restrict__ hb) {
    int e = blockIdx.x * 256 + threadIdx.x;   // e < NB*HID
    hb[e] = (_Float16)h0[e];
}

// x_proj chunk GEMM with PERMUTED output columns (unchanged)
__global__ __launch_bounds__(256) void xproj_gemm(const float* __restrict__ x,
                                                  const float* __restrict__ wih,
                                                  const float* __restrict__ bih,
                                                  const float* __restrict__ bhh,
                                                  float* __restrict__ xbuf,
                                                  int chunk, int SC) {
    __shared__ float As[16][68];
    __shared__ float Bs[16][68];
    const int m0 = blockIdx.x * 64;
    const int n0 = blockIdx.y * 64;
    const int tid = threadIdx.x;
    const int tx = tid % 16;
    const int ty = tid / 16;
    const int lr  = tid / 4;
    const int lc4 = tid % 4;

    float acc[4][4] = {};

    const int m = m0 + lr;
    const int b  = m / SC;
    const int tl = m % SC;
    const float* arow_base = x + ((size_t)b * SEQL + (size_t)chunk * SC + tl) * INPD + lc4 * 4;
    const float* brow_base = wih + (size_t)orig_gate(n0 + lr) * INPD + lc4 * 4;

    for (int k0 = 0; k0 < 512; k0 += 16) {
        float4 a4 = *(const float4*)(arow_base + k0);
        float4 b4 = *(const float4*)(brow_base + k0);
        As[lc4 * 4 + 0][lr] = a4.x;
        As[lc4 * 4 + 1][lr] = a4.y;
        As[lc4 * 4 + 2][lr] = a4.z;
        As[lc4 * 4 + 3][lr] = a4.w;
        Bs[lc4 * 4 + 0][lr] = b4.x;
        Bs[lc4 * 4 + 1][lr] = b4.y;
        Bs[lc4 * 4 + 2][lr] = b4.z;
        Bs[lc4 * 4 + 3][lr] = b4.w;
        __syncthreads();
        #pragma unroll
        for (int kk = 0; kk < 16; ++kk) {
            float4 av = *(const float4*)&As[kk][ty * 4];
            float4 bv = *(const float4*)&Bs[kk][tx * 4];
            float a[4] = {av.x, av.y, av.z, av.w};
            float bb[4] = {bv.x, bv.y, bv.z, bv.w};
            #pragma unroll
            for (int i = 0; i < 4; ++i)
                #pragma unroll
                for (int jj = 0; jj < 4; ++jj)
                    acc[i][jj] = fmaf(a[i], bb[jj], acc[i][jj]);
        }
        __syncthreads();
    }

    #pragma unroll
    for (int i = 0; i < 4; ++i) {
        int mo = m0 + ty * 4 + i;
        float* orow = xbuf + (size_t)mo * G4;
        #pragma unroll
        for (int jj = 0; jj < 4; ++jj) {
            int n = n0 + tx * 4 + jj;
            int og = orig_gate(n);
            orow[n] = acc[i][jj] + bih[og] + bhh[og];
        }
    }
}

// Persistent recurrence, minimal-structure MFMA version.
// 128 blocks x 512 threads (8 waves); block j owns units [4j,4j+4) = 16 gates.
// Per step:
//   - all waves poll flags >= g (each wave independently; no barrier after)
//   - A-frag (h rows) loaded DIRECTLY from hbuf via 8B LLC atomic loads -> regs
//   - B-frag (W rows) lives in 16 VGPRs, loaded once before the loop
//   - wave w (mt=w&1, kg=w>>1): 4 x mfma_f32_16x16x32_f16, partial C -> LDS
//     part[(reg*8+w)*67+lane]  (stride 67: bank-conflict-free 2-way, both sides)
//   - sync1; wave 0 (t<64): thread owns (batch b=t&31, unit pair pp=t>>5):
//     reduces 8 gates x 4 k-groups, cell update, packs half2, publishes to
//     hbuf[(g+1)&1] via relaxed LLC atomic store
//   - sync2 (implicit vmcnt(0) drains publish); t0 stores flags[j]=g+1;
//     out-store issued after arrive (ack overlaps next step's poll)
__global__ __launch_bounds__(512, 1)
void lstm_persist(const _Float16* __restrict__ wh,   // [NBLK][16][512] fp16
                  const float* __restrict__ xbuf,    // [NB*SC][G4] permuted
                  const float* __restrict__ c0,
                  unsigned long long* __restrict__ hbuf, // fp16 [2][NB][HID] as u64
                  float* __restrict__ cstate,        // [NB][HID]
                  float* __restrict__ out,           // [NB][SEQL][HID]
                  int* __restrict__ flags,           // [NBLK*32]
                  int step_base, int SC) {
    __shared__ __align__(16) float part[32 * 67];    // (reg*8+w)*67 + lane

    const int j  = blockIdx.x;
    const int t  = threadIdx.x;
    const int u0 = 4 * j;

    // ---- MFMA role
    const int w    = t >> 6, lane = t & 63;
    const int mt   = w & 1, kg = w >> 1;
    const int arow = 16 * mt + (lane & 15);   // batch row (A)
    const int p_b  = lane & 15;               // gate row p (B)
    const int klq  = (lane >> 4) * 2;         // u64 sub-offset in 32-half group

    // ---- reduce role (wave 0): b = t&31, unit pair pp = t>>5
    const int b_r = t & 31, pp = t >> 5;

    // ---- B fragment into registers, once (16 VGPRs)
    half8 wf[4];
    {
        const _Float16* wrow = wh + ((size_t)j * 16 + p_b) * 512 + kg * 128 + (lane >> 4) * 8;
        #pragma unroll
        for (int q = 0; q < 4; ++q)
            wf[q] = *(const half8*)(wrow + q * 32);
    }

    // ---- cell state
    float cA = 0.0f, cB = 0.0f;
    if (t < 64) {
        const float* cs = (step_base == 0 ? c0 : cstate) + b_r * HID + u0 + 2 * pp;
        float2 cv = *(const float2*)cs;
        cA = cv.x; cB = cv.y;
    }

    for (int s = 0; s < SC; ++s) {
        const int g = step_base + s;

        // ---- xg prefetch (wave 0 only; uniform branch): 8 gates
        float xg[8];
        if (t < 64) {
            const float* xrow = xbuf + ((size_t)b_r * SC + s) * G4 + 16 * j;
            #pragma unroll
            for (int ty = 0; ty < 4; ++ty) {
                xg[ty * 2 + 0] = xrow[ty * 4 + 2 * pp + 0];
                xg[ty * 2 + 1] = xrow[ty * 4 + 2 * pp + 1];
            }
        }

        // ---- poll: every wave waits for all 128 flags >= g
        for (;;) {
            int f0 = __hip_atomic_load(&flags[lane * 32], __ATOMIC_RELAXED,
                                       __HIP_MEMORY_SCOPE_AGENT);
            int f1 = __hip_atomic_load(&flags[(lane + 64) * 32], __ATOMIC_RELAXED,
                                       __HIP_MEMORY_SCOPE_AGENT);
            if (__all(f0 >= g && f1 >= g)) break;
            __builtin_amdgcn_s_sleep(1);
        }

        // ---- A fragments direct from hbuf (LLC), then 4 MFMA
        const unsigned long long* hs8 = hbuf + (size_t)(g & 1) * 4096
                                      + (size_t)arow * 128 + kg * 32 + klq;
        half8 av[4];
        #pragma unroll
        for (int q = 0; q < 4; ++q) {
            unsigned long long va = __hip_atomic_load(hs8 + q * 8,     __ATOMIC_RELAXED,
                                                      __HIP_MEMORY_SCOPE_AGENT);
            unsigned long long vb = __hip_atomic_load(hs8 + q * 8 + 1, __ATOMIC_RELAXED,
                                                      __HIP_MEMORY_SCOPE_AGENT);
            __builtin_memcpy(&av[q], &va, 8);
            __builtin_memcpy((char*)&av[q] + 8, &vb, 8);
        }
        f32x4 acc = {0.f, 0.f, 0.f, 0.f};
        #pragma unroll
        for (int q = 0; q < 4; ++q)
            acc = __builtin_amdgcn_mfma_f32_16x16x32_f16(av[q], wf[q], acc, 0, 0, 0);

        // ---- partial C -> LDS (stride-67 planes, conflict-free)
        #pragma unroll
        for (int r = 0; r < 4; ++r)
            part[(r * 8 + w) * 67 + lane] = acc[r];
        __syncthreads();   // sync1

        // ---- wave 0: reduce 4 k-groups, cell update, publish
        float hA = 0.0f, hB = 0.0f;
        if (t < 64) {
            const int mtb   = b_r >> 4;
            const int row16 = b_r & 15;
            const int reg   = row16 & 3;
            const int lsA   = (row16 >> 2) * 16 + 8 * pp;   // + e gives gate p
            float gs[8];
            #pragma unroll
            for (int e = 0; e < 8; ++e) {
                float sum = 0.0f;
                #pragma unroll
                for (int kgg = 0; kgg < 4; ++kgg)
                    sum += part[(reg * 8 + kgg * 2 + mtb) * 67 + lsA + e];
                gs[e] = sum;
            }
            // unit A (uu=2pp):  p=8pp+ty   -> gs[0..3], xg[ty*2]
            // unit B (uu=2pp+1):p=8pp+4+ty -> gs[4..7], xg[ty*2+1]
            float giA = gs[0] + xg[0], gfA = gs[1] + xg[2];
            float ggA = gs[2] + xg[4], goA = gs[3] + xg[6];
            float giB = gs[4] + xg[1], gfB = gs[5] + xg[3];
            float ggB = gs[6] + xg[5], goB = gs[7] + xg[7];
            cA = fmaf(sigm(gfA), cA, sigm(giA) * tanh_fast(ggA));
            hA = sigm(goA) * tanh_fast(cA);
            cB = fmaf(sigm(gfB), cB, sigm(giB) * tanh_fast(ggB));
            hB = sigm(goB) * tanh_fast(cB);

            _Float16 hv2[2] = {(_Float16)hA, (_Float16)hB};
            unsigned hu;
            __builtin_memcpy(&hu, hv2, 4);
            unsigned* hb32 = (unsigned*)hbuf;
            __hip_atomic_store(hb32 + (size_t)((g + 1) & 1) * 8192
                                    + b_r * 256 + (u0 >> 1) + pp,
                               hu, __ATOMIC_RELAXED, __HIP_MEMORY_SCOPE_AGENT);
        }
        __syncthreads();   // sync2: drains wave0's publish (vmcnt(0) before barrier)

        // ---- arrive
        if (t == 0)
            __hip_atomic_store(&flags[j * 32], g + 1,
                               __ATOMIC_RELAXED, __HIP_MEMORY_SCOPE_AGENT);

        // ---- out store (fp32) AFTER arrive: HBM ack overlaps next poll
        if (t < 64) {
            float2 ov; ov.x = hA; ov.y = hB;
            *(float2*)&out[((size_t)b_r * SEQL + g) * HID + u0 + 2 * pp] = ov;
        }
    }

    if (t < 64) {
        float2 cv; cv.x = cA; cv.y = cB;
        *(float2*)&cstate[b_r * HID + u0 + 2 * pp] = cv;
    }
}

__global__ __launch_bounds__(256) void finalize(const _Float16* __restrict__ hfin,
                                                const float* __restrict__ cs,
                                                float* __restrict__ out) {
    int i = blockIdx.x * blockDim.x + threadIdx.x;
    size_t base = (size_t)NB * SEQL * HID;
    if (i < NB * HID) {
        out[base + i] = (float)hfin[i];
        out[base + NB * HID + i] = cs[i];
    }
}

extern "C" void kernel_launch(void* const* d_in, const int* in_sizes, int n_in,
                              void* d_out, int out_size, void* d_ws, size_t ws_size,
                              hipStream_t stream) {
    const float* x   = (const float*)d_in[0];
    const float* h0  = (const float*)d_in[1];
    const float* c0  = (const float*)d_in[2];
    const float* wih = (const float*)d_in[3];
    const float* whh = (const float*)d_in[4];
    const float* bih = (const float*)d_in[5];
    const float* bhh = (const float*)d_in[6];
    float* out = (float*)d_out;

    char* ws = (char*)d_ws;
    int*       flags  = (int*)ws;                                  // 16 KB
    _Float16*  hbuf_h = (_Float16*)(ws + 16384);                   // 64 KB (2 bufs)
    float*     cstate = (float*)(ws + 16384 + 65536);              // 64 KB
    _Float16*  wh_h   = (_Float16*)(ws + 16384 + 65536 + 65536);   // 2 MB
    float*     xbuf   = (float*)(ws + 16384 + 65536 + 65536 + 2097152);

    size_t fixed = 16384 + 65536 + 65536 + 2097152;
    int SC = SEQL;
    while (SC > 64 && fixed + (size_t)NB * SC * G4 * sizeof(float) > ws_size) SC >>= 1;

    hipMemsetAsync(flags, 0, 16384, stream);
    conv_whh<<<(2048 * 512) / 256, 256, 0, stream>>>(whh, wh_h);
    conv_h0<<<(NB * HID) / 256, 256, 0, stream>>>(h0, hbuf_h);

    int nchunks = SEQL / SC;
    for (int ch = 0; ch < nchunks; ++ch) {
        dim3 grd(NB * SC / 64, G4 / 64);
        xproj_gemm<<<grd, 256, 0, stream>>>(x, wih, bih, bhh, xbuf, ch, SC);
        lstm_persist<<<NBLK, TPB, 0, stream>>>(wh_h, xbuf, c0,
                                               (unsigned long long*)hbuf_h,
                                               cstate, out, flags, ch * SC, SC);
    }

    // total steps = 1024 (even) -> final h parity is buffer 0
    finalize<<<(NB * HID + 255) / 256, 256, 0, stream>>>(hbuf_h, cstate, out);
}

// Round 14
// 4599.247 us; speedup vs baseline: 1.1475x; 1.1475x over previous
//
#include <hip/hip_runtime.h>
#include <cstddef>

#define HID   512
#define G4    2048   // 4*HID
#define NB    32     // batch
#define SEQL  1024
#define INPD  512
#define NBLK  128    // persistent blocks: block j owns hidden units [4j, 4j+4)
#define TPB   512

typedef _Float16 half8 __attribute__((ext_vector_type(8)));
typedef float    f32x4 __attribute__((ext_vector_type(4)));

__device__ __forceinline__ float sigm(float x) {
    return 1.0f / (1.0f + __expf(-x));
}
__device__ __forceinline__ float tanh_fast(float x) {
    float e = __expf(-2.0f * fabsf(x));
    float t = (1.0f - e) / (1.0f + e);
    return copysignf(t, x);
}

// p-major permuted gate index: g'' = j*16 + p, p = uu*4 + ty
// (uu = unit within block 0..3, ty = gate type). orig row = ty*HID + j*4 + uu.
__device__ __forceinline__ int orig_gate(int gp) {
    int p = gp & 15, j = gp >> 4;
    return (p & 3) * HID + j * 4 + (p >> 2);
}

// ---- one-time: W_hh fp32 [2048][512] -> fp16, wh[j][p][k], p = uu*4 + ty
__global__ __launch_bounds__(256) void conv_whh(const float* __restrict__ whh,
                                                _Float16* __restrict__ wh) {
    int e = blockIdx.x * 256 + threadIdx.x;   // e < 2048*512
    int R = e >> 9, k = e & 511;
    int ty = R >> 9, rem = R & 511;
    int j = rem >> 2, uu = rem & 3;
    int p = uu * 4 + ty;
    wh[((size_t)j * 16 + p) * 512 + k] = (_Float16)whh[e];
}

// ---- one-time: h0 fp32 -> fp16 into hbuf buffer 0
__global__ __launch_bounds__(256) void conv_h0(const float* __restrict__ h0,
                                               _Float16* __restrict__ hb) {
    int e = blockIdx.x * 256 + threadIdx.x;   // e < NB*HID
    hb[e] = (_Float16)h0[e];
}

// x_proj chunk GEMM with p-major PERMUTED output columns
__global__ __launch_bounds__(256) void xproj_gemm(const float* __restrict__ x,
                                                  const float* __restrict__ wih,
                                                  const float* __restrict__ bih,
                                                  const float* __restrict__ bhh,
                                                  float* __restrict__ xbuf,
                                                  int chunk, int SC) {
    __shared__ float As[16][68];
    __shared__ float Bs[16][68];
    const int m0 = blockIdx.x * 64;
    const int n0 = blockIdx.y * 64;
    const int tid = threadIdx.x;
    const int tx = tid % 16;
    const int ty = tid / 16;
    const int lr  = tid / 4;
    const int lc4 = tid % 4;

    float acc[4][4] = {};

    const int m = m0 + lr;
    const int b  = m / SC;
    const int tl = m % SC;
    const float* arow_base = x + ((size_t)b * SEQL + (size_t)chunk * SC + tl) * INPD + lc4 * 4;
    const float* brow_base = wih + (size_t)orig_gate(n0 + lr) * INPD + lc4 * 4;

    for (int k0 = 0; k0 < 512; k0 += 16) {
        float4 a4 = *(const float4*)(arow_base + k0);
        float4 b4 = *(const float4*)(brow_base + k0);
        As[lc4 * 4 + 0][lr] = a4.x;
        As[lc4 * 4 + 1][lr] = a4.y;
        As[lc4 * 4 + 2][lr] = a4.z;
        As[lc4 * 4 + 3][lr] = a4.w;
        Bs[lc4 * 4 + 0][lr] = b4.x;
        Bs[lc4 * 4 + 1][lr] = b4.y;
        Bs[lc4 * 4 + 2][lr] = b4.z;
        Bs[lc4 * 4 + 3][lr] = b4.w;
        __syncthreads();
        #pragma unroll
        for (int kk = 0; kk < 16; ++kk) {
            float4 av = *(const float4*)&As[kk][ty * 4];
            float4 bv = *(const float4*)&Bs[kk][tx * 4];
            float a[4] = {av.x, av.y, av.z, av.w};
            float bb[4] = {bv.x, bv.y, bv.z, bv.w};
            #pragma unroll
            for (int i = 0; i < 4; ++i)
                #pragma unroll
                for (int jj = 0; jj < 4; ++jj)
                    acc[i][jj] = fmaf(a[i], bb[jj], acc[i][jj]);
        }
        __syncthreads();
    }

    #pragma unroll
    for (int i = 0; i < 4; ++i) {
        int mo = m0 + ty * 4 + i;
        float* orow = xbuf + (size_t)mo * G4;
        #pragma unroll
        for (int jj = 0; jj < 4; ++jj) {
            int n = n0 + tx * 4 + jj;
            int og = orig_gate(n);
            orow[n] = acc[i][jj] + bih[og] + bhh[og];
        }
    }
}

// Persistent recurrence: r12 poll + r13 datapath, 3 barriers/step.
// 128 blocks x 512 threads (8 waves); block j owns units [4j,4j+4) = 16 gates
// (p-major: p = uu*4+ty).
// Per step:
//   xg prefetch (t<64: 2 float4, contiguous thanks to p-major perm)
//   poll: t<128 spins on own flag line; __syncthreads releases all
//   A-frag direct from hbuf (8 u64 LLC atomic loads) -> 4 MFMA (B in VGPRs)
//   part write (stride-67 planes) ; sync
//   t<64: reduce 4 k-groups x 8 gates, cell update, publish fp16 pair ; sync
//   t0: arrive flag ; t<64: out store (HBM ack overlaps next poll)
__global__ __launch_bounds__(512, 1)
void lstm_persist(const _Float16* __restrict__ wh,   // [NBLK][16][512] fp16
                  const float* __restrict__ xbuf,    // [NB*SC][G4] p-major perm
                  const float* __restrict__ c0,
                  unsigned long long* __restrict__ hbuf, // fp16 [2][NB][HID] as u64
                  float* __restrict__ cstate,        // [NB][HID]
                  float* __restrict__ out,           // [NB][SEQL][HID]
                  int* __restrict__ flags,           // [NBLK*32]
                  int step_base, int SC) {
    __shared__ __align__(16) float part[32 * 67];    // (reg*8+w)*67 + lane

    const int j  = blockIdx.x;
    const int t  = threadIdx.x;
    const int u0 = 4 * j;

    // ---- MFMA role
    const int w    = t >> 6, lane = t & 63;
    const int mt   = w & 1, kg = w >> 1;
    const int arow = 16 * mt + (lane & 15);   // batch row (A)
    const int p_b  = lane & 15;               // gate row p (B)
    const int klq  = (lane >> 4) * 2;         // u64 sub-offset in 32-half group

    // ---- reduce role (t<64): b = t&31, unit pair pp = t>>5
    const int b_r = t & 31, pp = t >> 5;

    // ---- B fragment into registers, once (16 VGPRs)
    half8 wf[4];
    {
        const _Float16* wrow = wh + ((size_t)j * 16 + p_b) * 512 + kg * 128 + (lane >> 4) * 8;
        #pragma unroll
        for (int q = 0; q < 4; ++q)
            wf[q] = *(const half8*)(wrow + q * 32);
    }

    // ---- cell state
    float cA = 0.0f, cB = 0.0f;
    if (t < 64) {
        const float* cs = (step_base == 0 ? c0 : cstate) + b_r * HID + u0 + 2 * pp;
        float2 cv = *(const float2*)cs;
        cA = cv.x; cB = cv.y;
    }

    for (int s = 0; s < SC; ++s) {
        const int g = step_base + s;

        // ---- xg prefetch: 8 contiguous gates = 2 float4
        float4 x0 = {0,0,0,0}, x1 = {0,0,0,0};
        if (t < 64) {
            const float* xrow = xbuf + ((size_t)b_r * SC + s) * G4 + 16 * j + 8 * pp;
            x0 = *(const float4*)(xrow);
            x1 = *(const float4*)(xrow + 4);
        }

        // ---- poll: t<128 spins on own flag line, barrier releases all
        if (t < NBLK) {
            while (__hip_atomic_load(&flags[t * 32], __ATOMIC_RELAXED,
                                     __HIP_MEMORY_SCOPE_AGENT) < g)
                __builtin_amdgcn_s_sleep(1);
        }
        __syncthreads();   // sync_poll (also orders part-buffer reuse)

        // ---- A fragments direct from hbuf (LLC), then 4 MFMA
        const unsigned long long* hs8 = hbuf + (size_t)(g & 1) * 4096
                                      + (size_t)arow * 128 + kg * 32 + klq;
        half8 av[4];
        #pragma unroll
        for (int q = 0; q < 4; ++q) {
            unsigned long long va = __hip_atomic_load(hs8 + q * 8,     __ATOMIC_RELAXED,
                                                      __HIP_MEMORY_SCOPE_AGENT);
            unsigned long long vb = __hip_atomic_load(hs8 + q * 8 + 1, __ATOMIC_RELAXED,
                                                      __HIP_MEMORY_SCOPE_AGENT);
            __builtin_memcpy(&av[q], &va, 8);
            __builtin_memcpy((char*)&av[q] + 8, &vb, 8);
        }
        f32x4 acc = {0.f, 0.f, 0.f, 0.f};
        #pragma unroll
        for (int q = 0; q < 4; ++q)
            acc = __builtin_amdgcn_mfma_f32_16x16x32_f16(av[q], wf[q], acc, 0, 0, 0);

        // ---- partial C -> LDS (stride-67 planes, conflict-free)
        #pragma unroll
        for (int r = 0; r < 4; ++r)
            part[(r * 8 + w) * 67 + lane] = acc[r];
        __syncthreads();   // sync_part

        // ---- t<64: reduce 4 k-groups, cell update, publish
        float hA = 0.0f, hB = 0.0f;
        if (t < 64) {
            const int mtb   = b_r >> 4;
            const int row16 = b_r & 15;
            const int reg   = row16 & 3;
            const int lsA   = (row16 >> 2) * 16 + 8 * pp;   // + e gives gate p
            float gs[8];
            #pragma unroll
            for (int e = 0; e < 8; ++e) {
                float sum = 0.0f;
                #pragma unroll
                for (int kgg = 0; kgg < 4; ++kgg)
                    sum += part[(reg * 8 + kgg * 2 + mtb) * 67 + lsA + e];
                gs[e] = sum;
            }
            // p-major: unit A (uu=2pp): p=8pp+ty -> gs[0..3]+x0
            //          unit B (uu=2pp+1): p=8pp+4+ty -> gs[4..7]+x1
            float giA = gs[0] + x0.x, gfA = gs[1] + x0.y;
            float ggA = gs[2] + x0.z, goA = gs[3] + x0.w;
            float giB = gs[4] + x1.x, gfB = gs[5] + x1.y;
            float ggB = gs[6] + x1.z, goB = gs[7] + x1.w;
            cA = fmaf(sigm(gfA), cA, sigm(giA) * tanh_fast(ggA));
            hA = sigm(goA) * tanh_fast(cA);
            cB = fmaf(sigm(gfB), cB, sigm(giB) * tanh_fast(ggB));
            hB = sigm(goB) * tanh_fast(cB);

            _Float16 hv2[2] = {(_Float16)hA, (_Float16)hB};
            unsigned hu;
            __builtin_memcpy(&hu, hv2, 4);
            unsigned* hb32 = (unsigned*)hbuf;
            __hip_atomic_store(hb32 + (size_t)((g + 1) & 1) * 8192
                                    + b_r * 256 + (u0 >> 1) + pp,
                               hu, __ATOMIC_RELAXED, __HIP_MEMORY_SCOPE_AGENT);
        }
        __syncthreads();   // sync_drain: publish acked at LLC before flag

        // ---- arrive
        if (t == 0)
            __hip_atomic_store(&flags[j * 32], g + 1,
                               __ATOMIC_RELAXED, __HIP_MEMORY_SCOPE_AGENT);

        // ---- out store (fp32) AFTER arrive: HBM ack overlaps next poll
        if (t < 64) {
            float2 ov; ov.x = hA; ov.y = hB;
            *(float2*)&out[((size_t)b_r * SEQL + g) * HID + u0 + 2 * pp] = ov;
        }
    }

    if (t < 64) {
        float2 cv; cv.x = cA; cv.y = cB;
        *(float2*)&cstate[b_r * HID + u0 + 2 * pp] = cv;
    }
}

__global__ __launch_bounds__(256) void finalize(const _Float16* __restrict__ hfin,
                                                const float* __restrict__ cs,
                                                float* __restrict__ out) {
    int i = blockIdx.x * blockDim.x + threadIdx.x;
    size_t base = (size_t)NB * SEQL * HID;
    if (i < NB * HID) {
        out[base + i] = (float)hfin[i];
        out[base + NB * HID + i] = cs[i];
    }
}

extern "C" void kernel_launch(void* const* d_in, const int* in_sizes, int n_in,
                              void* d_out, int out_size, void* d_ws, size_t ws_size,
                              hipStream_t stream) {
    const float* x   = (const float*)d_in[0];
    const float* h0  = (const float*)d_in[1];
    const float* c0  = (const float*)d_in[2];
    const float* wih = (const float*)d_in[3];
    const float* whh = (const float*)d_in[4];
    const float* bih = (const float*)d_in[5];
    const float* bhh = (const float*)d_in[6];
    float* out = (float*)d_out;

    char* ws = (char*)d_ws;
    int*       flags  = (int*)ws;                                  // 16 KB
    _Float16*  hbuf_h = (_Float16*)(ws + 16384);                   // 64 KB (2 bufs)
    float*     cstate = (float*)(ws + 16384 + 65536);              // 64 KB
    _Float16*  wh_h   = (_Float16*)(ws + 16384 + 65536 + 65536);   // 2 MB
    float*     xbuf   = (float*)(ws + 16384 + 65536 + 65536 + 2097152);

    size_t fixed = 16384 + 65536 + 65536 + 2097152;
    int SC = SEQL;
    while (SC > 64 && fixed + (size_t)NB * SC * G4 * sizeof(float) > ws_size) SC >>= 1;

    hipMemsetAsync(flags, 0, 16384, stream);
    conv_whh<<<(2048 * 512) / 256, 256, 0, stream>>>(whh, wh_h);
    conv_h0<<<(NB * HID) / 256, 256, 0, stream>>>(h0, hbuf_h);

    int nchunks = SEQL / SC;
    for (int ch = 0; ch < nchunks; ++ch) {
        dim3 grd(NB * SC / 64, G4 / 64);
        xproj_gemm<<<grd, 256, 0, stream>>>(x, wih, bih, bhh, xbuf, ch, SC);
        lstm_persist<<<NBLK, TPB, 0, stream>>>(wh_h, xbuf, c0,
                                               (unsigned long long*)hbuf_h,
                                               cstate, out, flags, ch * SC, SC);
    }

    // total steps = 1024 (even) -> final h parity is buffer 0
    finalize<<<(NB * HID + 255) / 256, 256, 0, stream>>>(hbuf_h, cstate, out);
}